// Round 1
// baseline (165.483 us; speedup 1.0000x reference)
//
#include <hip/hip_runtime.h>
#include <hip/hip_bf16.h>

// N=2048, D_IN=128, H=256, D_EMB=64
// inputs: 0:x 1:adj(unused) 2:W0 3:b0 4:W1 5:b1 6:W2 7:b2 8:temp 9:theta
// d_out: out[2048*128] then adj_wts[2048*2048]

typedef short bf16x8 __attribute__((ext_vector_type(8)));
typedef float f32x4 __attribute__((ext_vector_type(4)));

__device__ __forceinline__ unsigned short f2bf(float f) {
    unsigned u = __float_as_uint(f);
    unsigned r = u + 0x7fffu + ((u >> 16) & 1u);
    return (unsigned short)(r >> 16);
}

// ---------------- Kernel 1: fused MLP (f32) ----------------
// block = 256 threads, 16 rows per block, grid = 128
__global__ __launch_bounds__(256) void k1_mlp(
    const float* __restrict__ x,
    const float* __restrict__ W0, const float* __restrict__ b0,
    const float* __restrict__ W1, const float* __restrict__ b1,
    const float* __restrict__ W2, const float* __restrict__ b2,
    unsigned short* __restrict__ emb_bf,   // [2048][64] bf16
    unsigned short* __restrict__ xlT_bf,   // [128][2048] bf16 (transposed x_last)
    float* __restrict__ sq,                // [2048]
    float* __restrict__ deg)               // [2048] zero-init here
{
    __shared__ float xs[16 * 132];    // x tile, stride 132 (528B, 16B-mult)
    __shared__ float oxs[16 * 260];   // out_x tile, stride 260 (1040B, 16B-mult)
    const int t = threadIdx.x;
    const int r0 = blockIdx.x * 16;

    // load x tile (16x128 f32) coalesced
    for (int id = t; id < 512; id += 256) {
        int row = id >> 5, c4 = id & 31;
        float4 v = *(const float4*)(x + (r0 + row) * 128 + c4 * 4);
        *(float4*)(&xs[row * 132 + c4 * 4]) = v;
    }
    if (t < 16) deg[r0 + t] = 0.0f;
    __syncthreads();

    // Phase A: out_x = relu(x@W0+b0). thread t -> column h=t, all 16 rows.
    {
        float acc0[16];
        float bb = b0[t];
        #pragma unroll
        for (int r = 0; r < 16; ++r) acc0[r] = bb;
        for (int kk = 0; kk < 32; ++kk) {
            float wa = W0[(kk * 4 + 0) * 256 + t];
            float wb = W0[(kk * 4 + 1) * 256 + t];
            float wc = W0[(kk * 4 + 2) * 256 + t];
            float wd = W0[(kk * 4 + 3) * 256 + t];
            #pragma unroll
            for (int r = 0; r < 16; ++r) {
                float4 xv = *(const float4*)(&xs[r * 132 + kk * 4]);
                acc0[r] += xv.x * wa + xv.y * wb + xv.z * wc + xv.w * wd;
            }
        }
        #pragma unroll
        for (int r = 0; r < 16; ++r) oxs[r * 260 + t] = fmaxf(acc0[r], 0.0f);
    }
    __syncthreads();

    // Phase B: emb = relu(out_x@W1+b1). thread: col h=t&63, rows rg*4..+3 (rg = wave id)
    {
        int h = t & 63;
        int rg = t >> 6;
        float acc1[4];
        float bb = b1[h];
        #pragma unroll
        for (int r = 0; r < 4; ++r) acc1[r] = bb;
        for (int kk = 0; kk < 64; ++kk) {
            float wa = W1[(kk * 4 + 0) * 64 + h];
            float wb = W1[(kk * 4 + 1) * 64 + h];
            float wc = W1[(kk * 4 + 2) * 64 + h];
            float wd = W1[(kk * 4 + 3) * 64 + h];
            #pragma unroll
            for (int r = 0; r < 4; ++r) {
                float4 xv = *(const float4*)(&oxs[(rg * 4 + r) * 260 + kk * 4]);
                acc1[r] += xv.x * wa + xv.y * wb + xv.z * wc + xv.w * wd;
            }
        }
        #pragma unroll
        for (int r = 0; r < 4; ++r) {
            float e = fmaxf(acc1[r], 0.0f);
            int row = r0 + rg * 4 + r;
            emb_bf[row * 64 + h] = f2bf(e);
            float s = e * e;
            #pragma unroll
            for (int off = 32; off; off >>= 1) s += __shfl_xor(s, off);
            if (h == 0) sq[row] = s;
        }
    }

    // Phase C: x_last = x@W2+b2 (NO relu). thread: col c=t&127, rows rg*8..+7
    {
        int c = t & 127;
        int rg = t >> 7;
        float acc2[8];
        float bb = b2[c];
        #pragma unroll
        for (int r = 0; r < 8; ++r) acc2[r] = bb;
        for (int kk = 0; kk < 32; ++kk) {
            float wa = W2[(kk * 4 + 0) * 128 + c];
            float wb = W2[(kk * 4 + 1) * 128 + c];
            float wc = W2[(kk * 4 + 2) * 128 + c];
            float wd = W2[(kk * 4 + 3) * 128 + c];
            #pragma unroll
            for (int r = 0; r < 8; ++r) {
                float4 xv = *(const float4*)(&xs[(rg * 8 + r) * 132 + kk * 4]);
                acc2[r] += xv.x * wa + xv.y * wb + xv.z * wc + xv.w * wd;
            }
        }
        unsigned short pack[8];
        #pragma unroll
        for (int r = 0; r < 8; ++r) pack[r] = f2bf(acc2[r]);
        *(uint4*)(&xlT_bf[c * 2048 + r0 + rg * 8]) = *(uint4*)pack;
    }
}

// ---------------- Kernel 2: adjacency + A@x_last (bf16 MFMA) ----------------
// block = 256 (4 waves), 16 rows per block; grid = (128 i-tiles, 2 j-halves)
__global__ __launch_bounds__(256) void k2_adj(
    const unsigned short* __restrict__ emb_bf,
    const unsigned short* __restrict__ xlT_bf,
    const float* __restrict__ sq,
    const float* __restrict__ tempp, const float* __restrict__ thetap,
    float* __restrict__ outAcc,   // d_out[0..262143], zeroed by memset
    float* __restrict__ adjw,     // d_out + 262144
    float* __restrict__ deg)
{
    constexpr int LD = 88;  // padded row stride in bf16 elems (176B: 16B-mult, conflict-safe)
    __shared__ unsigned short embI[16 * LD];
    __shared__ unsigned short embJ[64 * LD];
    __shared__ unsigned short xlT[128 * LD];
    __shared__ unsigned short Ald[16 * LD];
    __shared__ float sqJ[64];
    __shared__ float sqI[16];

    const int t = threadIdx.x;
    const int lane = t & 63;
    const int w = t >> 6;        // wave id 0..3
    const int m = lane & 15;
    const int q = lane >> 4;
    const int i0 = blockIdx.x * 16;
    const int jbase = blockIdx.y * 1024;
    const float scale = 1.0f + tempp[0];
    const float bias = 5.0f + thetap[0];

    // stage embI (16x64 bf16) + sqI
    if (t < 128) {
        int row = t >> 3, off = t & 7;
        uint4 v = *(const uint4*)(emb_bf + (i0 + row) * 64 + off * 8);
        *(uint4*)(&embI[row * LD + off * 8]) = v;
    }
    if (t < 16) sqI[t] = sq[i0 + t];

    f32x4 accF0 = {0.f, 0.f, 0.f, 0.f};
    f32x4 accF1 = {0.f, 0.f, 0.f, 0.f};
    float dega[4] = {0.f, 0.f, 0.f, 0.f};

    for (int jt = 0; jt < 16; ++jt) {
        const int j0 = jbase + jt * 64;
        __syncthreads();  // previous iter's LDS consumers done (iter0: nothing)
        // load embJ: 64 rows x 64 bf16
        for (int ch = t; ch < 512; ch += 256) {
            int row = ch >> 3, off = ch & 7;
            uint4 v = *(const uint4*)(emb_bf + (j0 + row) * 64 + off * 8);
            *(uint4*)(&embJ[row * LD + off * 8]) = v;
        }
        // load xlT slice: 128 rows x 64 bf16 (k = j0..j0+63)
        for (int ch = t; ch < 1024; ch += 256) {
            int row = ch >> 3, off = ch & 7;
            uint4 v = *(const uint4*)(xlT_bf + row * 2048 + j0 + off * 8);
            *(uint4*)(&xlT[row * LD + off * 8]) = v;
        }
        if (t < 64) sqJ[t] = sq[j0 + t];
        __syncthreads();

        // S phase: wave w computes S[:, 16w..16w+15] = embI @ embJ^T (K=64)
        bf16x8 a0 = *(const bf16x8*)(&embI[m * LD + q * 8]);
        bf16x8 a1 = *(const bf16x8*)(&embI[m * LD + 32 + q * 8]);
        int jc = w * 16 + m;
        bf16x8 b0v = *(const bf16x8*)(&embJ[jc * LD + q * 8]);
        bf16x8 b1v = *(const bf16x8*)(&embJ[jc * LD + 32 + q * 8]);
        f32x4 S = {0.f, 0.f, 0.f, 0.f};
        S = __builtin_amdgcn_mfma_f32_16x16x32_bf16(a0, b0v, S, 0, 0, 0);
        S = __builtin_amdgcn_mfma_f32_16x16x32_bf16(a1, b1v, S, 0, 0, 0);

        // C layout: col = lane&15 (=m), row = q*4+reg
        float csqJ = sqJ[w * 16 + m];
        int gcol = j0 + w * 16 + m;
        #pragma unroll
        for (int r = 0; r < 4; ++r) {
            int grow = i0 + q * 4 + r;
            float dist = 2.0f * S[r] - sqI[q * 4 + r] - csqJ;
            float z = scale * dist + bias;
            float p = 1.0f / (1.0f + __expf(-z));
            if (grow == gcol) p += 1.0f;
            adjw[grow * 2048 + gcol] = p;
            dega[r] += p;
            Ald[(q * 4 + r) * LD + w * 16 + m] = f2bf(p);
        }
        __syncthreads();

        // AX phase: wave w covers x-cols 32w..32w+31 (2 MFMA tiles), K=64 over j
        bf16x8 aa0 = *(const bf16x8*)(&Ald[m * LD + q * 8]);
        bf16x8 aa1 = *(const bf16x8*)(&Ald[m * LD + 32 + q * 8]);
        {
            int n0 = w * 32 + m;
            bf16x8 bb0 = *(const bf16x8*)(&xlT[n0 * LD + q * 8]);
            bf16x8 bb1 = *(const bf16x8*)(&xlT[n0 * LD + 32 + q * 8]);
            accF0 = __builtin_amdgcn_mfma_f32_16x16x32_bf16(aa0, bb0, accF0, 0, 0, 0);
            accF0 = __builtin_amdgcn_mfma_f32_16x16x32_bf16(aa1, bb1, accF0, 0, 0, 0);
            int n1 = w * 32 + 16 + m;
            bf16x8 cc0 = *(const bf16x8*)(&xlT[n1 * LD + q * 8]);
            bf16x8 cc1 = *(const bf16x8*)(&xlT[n1 * LD + 32 + q * 8]);
            accF1 = __builtin_amdgcn_mfma_f32_16x16x32_bf16(aa0, cc0, accF1, 0, 0, 0);
            accF1 = __builtin_amdgcn_mfma_f32_16x16x32_bf16(aa1, cc1, accF1, 0, 0, 0);
        }
    }

    // deg: reduce across the 16 lanes sharing a quad (cols), then atomic
    #pragma unroll
    for (int r = 0; r < 4; ++r) {
        float v = dega[r];
        v += __shfl_xor(v, 1);
        v += __shfl_xor(v, 2);
        v += __shfl_xor(v, 4);
        v += __shfl_xor(v, 8);
        if (m == 0) atomicAdd(&deg[i0 + q * 4 + r], v);
    }
    // accumulate partial A@x_last into outAcc
    #pragma unroll
    for (int r = 0; r < 4; ++r) {
        int row = i0 + q * 4 + r;
        atomicAdd(&outAcc[row * 128 + w * 32 + m], accF0[r]);
        atomicAdd(&outAcc[row * 128 + w * 32 + 16 + m], accF1[r]);
    }
}

// ---------------- Kernel 3: out = relu(acc/deg), in place ----------------
__global__ __launch_bounds__(256) void k3_fin(float* __restrict__ out,
                                              const float* __restrict__ deg) {
    int idx = blockIdx.x * 256 + threadIdx.x;
    float v = out[idx] / deg[idx >> 7];
    out[idx] = fmaxf(v, 0.0f);
}

extern "C" void kernel_launch(void* const* d_in, const int* in_sizes, int n_in,
                              void* d_out, int out_size, void* d_ws, size_t ws_size,
                              hipStream_t stream) {
    const float* x     = (const float*)d_in[0];
    // d_in[1] = adj: never read (only shape matters)
    const float* W0    = (const float*)d_in[2];
    const float* b0    = (const float*)d_in[3];
    const float* W1    = (const float*)d_in[4];
    const float* b1    = (const float*)d_in[5];
    const float* W2    = (const float*)d_in[6];
    const float* b2    = (const float*)d_in[7];
    const float* temp  = (const float*)d_in[8];
    const float* theta = (const float*)d_in[9];

    // workspace layout
    char* ws = (char*)d_ws;
    unsigned short* emb_bf = (unsigned short*)(ws);            // 262144 B
    unsigned short* xlT_bf = (unsigned short*)(ws + 262144);   // 524288 B
    float* sq  = (float*)(ws + 786432);                        // 8192 B
    float* deg = (float*)(ws + 794624);                        // 8192 B

    float* outAcc = (float*)d_out;            // [2048*128]
    float* adjw   = (float*)d_out + 262144;   // [2048*2048]

    // zero the out accumulator (graph-capturable)
    hipMemsetAsync(outAcc, 0, 262144 * sizeof(float), stream);

    k1_mlp<<<128, 256, 0, stream>>>(x, W0, b0, W1, b1, W2, b2,
                                    emb_bf, xlT_bf, sq, deg);
    k2_adj<<<dim3(128, 2), 256, 0, stream>>>(emb_bf, xlT_bf, sq, temp, theta,
                                             outAcc, adjw, deg);
    k3_fin<<<1024, 256, 0, stream>>>(outAcc, deg);
}

// Round 2
// 118.091 us; speedup vs baseline: 1.4013x; 1.4013x over previous
//
#include <hip/hip_runtime.h>
#include <hip/hip_bf16.h>

// N=2048, D_IN=128, H=256, D_EMB=64
// inputs: 0:x 1:adj(unused) 2:W0 3:b0 4:W1 5:b1 6:W2 7:b2 8:temp 9:theta
// d_out: out[2048*128] then adj_wts[2048*2048]

typedef short bf16x8 __attribute__((ext_vector_type(8)));
typedef float f32x4 __attribute__((ext_vector_type(4)));

__device__ __forceinline__ unsigned short f2bf(float f) {
    unsigned u = __float_as_uint(f);
    unsigned r = u + 0x7fffu + ((u >> 16) & 1u);
    return (unsigned short)(r >> 16);
}

// ---------------- Kernel 1: fused MLP (f32) ----------------
// 256 blocks x 512 threads, 8 rows per block.
__global__ __launch_bounds__(512) void k1_mlp(
    const float* __restrict__ x,
    const float* __restrict__ W0, const float* __restrict__ b0,
    const float* __restrict__ W1, const float* __restrict__ b1,
    const float* __restrict__ W2, const float* __restrict__ b2,
    unsigned short* __restrict__ emb_bf,   // [2048][64] bf16
    unsigned short* __restrict__ xlT_bf,   // [128][2048] bf16 (transposed x_last)
    float* __restrict__ sq)                // [2048]
{
    __shared__ float xs[8 * 132];
    __shared__ float oxs[8 * 260];
    __shared__ unsigned short xls[128 * 8];
    const int t = threadIdx.x;
    const int r0 = blockIdx.x * 8;

    // load x tile (8x128 f32)
    if (t < 256) {
        int row = t >> 5, c4 = t & 31;
        float4 v = *(const float4*)(x + (r0 + row) * 128 + c4 * 4);
        *(float4*)(&xs[row * 132 + c4 * 4]) = v;
    }
    __syncthreads();

    // Phase A: out_x = relu(x@W0+b0). thread -> col c=t&255, rows rg*4..+3 (rg=t>>8)
    {
        int c = t & 255, rg = t >> 8;
        float bb = b0[c];
        float acc[4] = {bb, bb, bb, bb};
        for (int kk = 0; kk < 32; ++kk) {
            float wa = W0[(kk * 4 + 0) * 256 + c];
            float wb = W0[(kk * 4 + 1) * 256 + c];
            float wc = W0[(kk * 4 + 2) * 256 + c];
            float wd = W0[(kk * 4 + 3) * 256 + c];
            #pragma unroll
            for (int r = 0; r < 4; ++r) {
                float4 xv = *(const float4*)(&xs[(rg * 4 + r) * 132 + kk * 4]);
                acc[r] += xv.x * wa + xv.y * wb + xv.z * wc + xv.w * wd;
            }
        }
        #pragma unroll
        for (int r = 0; r < 4; ++r) oxs[(rg * 4 + r) * 260 + c] = fmaxf(acc[r], 0.0f);
    }
    __syncthreads();

    // Phase B: emb = relu(out_x@W1+b1). thread -> row r=t>>6 (one row per wave), col h=t&63
    {
        int h = t & 63, r = t >> 6;
        float acc = b1[h];
        for (int kk = 0; kk < 64; ++kk) {
            float wa = W1[(kk * 4 + 0) * 64 + h];
            float wb = W1[(kk * 4 + 1) * 64 + h];
            float wc = W1[(kk * 4 + 2) * 64 + h];
            float wd = W1[(kk * 4 + 3) * 64 + h];
            float4 xv = *(const float4*)(&oxs[r * 260 + kk * 4]);
            acc += xv.x * wa + xv.y * wb + xv.z * wc + xv.w * wd;
        }
        float e = fmaxf(acc, 0.0f);
        emb_bf[(r0 + r) * 64 + h] = f2bf(e);
        float s = e * e;
        #pragma unroll
        for (int off = 32; off; off >>= 1) s += __shfl_xor(s, off);
        if (h == 0) sq[r0 + r] = s;
    }

    // Phase C: x_last = x@W2+b2 (no relu). thread -> col c=t&127, rows rg*2..+1 (rg=t>>7)
    {
        int c = t & 127, rg = t >> 7;
        float bb = b2[c];
        float acc[2] = {bb, bb};
        for (int kk = 0; kk < 32; ++kk) {
            float wa = W2[(kk * 4 + 0) * 128 + c];
            float wb = W2[(kk * 4 + 1) * 128 + c];
            float wc = W2[(kk * 4 + 2) * 128 + c];
            float wd = W2[(kk * 4 + 3) * 128 + c];
            #pragma unroll
            for (int r = 0; r < 2; ++r) {
                float4 xv = *(const float4*)(&xs[(rg * 2 + r) * 132 + kk * 4]);
                acc[r] += xv.x * wa + xv.y * wb + xv.z * wc + xv.w * wd;
            }
        }
        unsigned short p0 = f2bf(acc[0]), p1 = f2bf(acc[1]);
        *(unsigned int*)(&xls[c * 8 + rg * 2]) = (unsigned)p0 | ((unsigned)p1 << 16);
    }
    __syncthreads();
    // coalesce xlT store: thread t<128 writes 8 bf16 (16B) for column t
    if (t < 128) {
        uint4 v = *(const uint4*)(&xls[t * 8]);
        *(uint4*)(&xlT_bf[t * 2048 + r0]) = v;
    }
}

// ---------------- Kernel 2: adjacency + A@x_last partials (bf16 MFMA) ----------------
// grid (128 i-tiles, P j-strips) x 256 threads; each block: 16 i-rows x (iters*64) j-cols.
__global__ __launch_bounds__(256) void k2_adj(
    const unsigned short* __restrict__ emb_bf,
    const unsigned short* __restrict__ xlT_bf,
    const float* __restrict__ sq,
    const float* __restrict__ tempp, const float* __restrict__ thetap,
    float* __restrict__ outPart,   // [P][2048][128]
    float* __restrict__ degPart,   // [P][2048]
    float* __restrict__ adjw,      // [2048][2048]
    int iters)
{
    constexpr int LD = 88;
    __shared__ unsigned short embI[16 * LD];
    __shared__ unsigned short embJ[64 * LD];
    __shared__ unsigned short xlT[128 * LD];
    __shared__ unsigned short Ald[16 * LD];
    __shared__ float sqJ[64];
    __shared__ float sqI[16];
    __shared__ float degS[64];

    const int t = threadIdx.x;
    const int lane = t & 63;
    const int w = t >> 6;
    const int m = lane & 15;
    const int q = lane >> 4;
    const int i0 = blockIdx.x * 16;
    const int bj = blockIdx.y;
    const int jbase = bj * (iters * 64);
    const float scale = 1.0f + tempp[0];
    const float bias = 5.0f + thetap[0];

    if (t < 128) {
        int row = t >> 3, off = t & 7;
        uint4 v = *(const uint4*)(emb_bf + (i0 + row) * 64 + off * 8);
        *(uint4*)(&embI[row * LD + off * 8]) = v;
    }
    if (t < 16) sqI[t] = sq[i0 + t];

    f32x4 accF0 = {0.f, 0.f, 0.f, 0.f};
    f32x4 accF1 = {0.f, 0.f, 0.f, 0.f};
    float dega[4] = {0.f, 0.f, 0.f, 0.f};

    for (int jt = 0; jt < iters; ++jt) {
        const int j0 = jbase + jt * 64;
        __syncthreads();  // guard LDS reuse from previous iteration
        for (int ch = t; ch < 512; ch += 256) {
            int row = ch >> 3, off = ch & 7;
            uint4 v = *(const uint4*)(emb_bf + (j0 + row) * 64 + off * 8);
            *(uint4*)(&embJ[row * LD + off * 8]) = v;
        }
        for (int ch = t; ch < 1024; ch += 256) {
            int row = ch >> 3, off = ch & 7;
            uint4 v = *(const uint4*)(xlT_bf + row * 2048 + j0 + off * 8);
            *(uint4*)(&xlT[row * LD + off * 8]) = v;
        }
        if (t < 64) sqJ[t] = sq[j0 + t];
        __syncthreads();

        // S phase: wave w computes S[:, 16w..16w+15] = embI @ embJ^T (K=64)
        bf16x8 a0 = *(const bf16x8*)(&embI[m * LD + q * 8]);
        bf16x8 a1 = *(const bf16x8*)(&embI[m * LD + 32 + q * 8]);
        int jc = w * 16 + m;
        bf16x8 b0v = *(const bf16x8*)(&embJ[jc * LD + q * 8]);
        bf16x8 b1v = *(const bf16x8*)(&embJ[jc * LD + 32 + q * 8]);
        f32x4 S = {0.f, 0.f, 0.f, 0.f};
        S = __builtin_amdgcn_mfma_f32_16x16x32_bf16(a0, b0v, S, 0, 0, 0);
        S = __builtin_amdgcn_mfma_f32_16x16x32_bf16(a1, b1v, S, 0, 0, 0);

        float csqJ = sqJ[w * 16 + m];
        int gcol = j0 + w * 16 + m;
        #pragma unroll
        for (int r = 0; r < 4; ++r) {
            int grow = i0 + q * 4 + r;
            float dist = 2.0f * S[r] - sqI[q * 4 + r] - csqJ;
            float z = scale * dist + bias;
            float p = 1.0f / (1.0f + __expf(-z));
            if (grow == gcol) p += 1.0f;
            adjw[grow * 2048 + gcol] = p;
            dega[r] += p;
            Ald[(q * 4 + r) * LD + w * 16 + m] = f2bf(p);
        }
        __syncthreads();

        // AX phase: wave w covers x-cols 32w..32w+31, K=64 over j
        bf16x8 aa0 = *(const bf16x8*)(&Ald[m * LD + q * 8]);
        bf16x8 aa1 = *(const bf16x8*)(&Ald[m * LD + 32 + q * 8]);
        int n0 = w * 32 + m;
        bf16x8 bb0 = *(const bf16x8*)(&xlT[n0 * LD + q * 8]);
        bf16x8 bb1 = *(const bf16x8*)(&xlT[n0 * LD + 32 + q * 8]);
        accF0 = __builtin_amdgcn_mfma_f32_16x16x32_bf16(aa0, bb0, accF0, 0, 0, 0);
        accF0 = __builtin_amdgcn_mfma_f32_16x16x32_bf16(aa1, bb1, accF0, 0, 0, 0);
        int n1 = w * 32 + 16 + m;
        bf16x8 cc0 = *(const bf16x8*)(&xlT[n1 * LD + q * 8]);
        bf16x8 cc1 = *(const bf16x8*)(&xlT[n1 * LD + 32 + q * 8]);
        accF1 = __builtin_amdgcn_mfma_f32_16x16x32_bf16(aa0, cc0, accF1, 0, 0, 0);
        accF1 = __builtin_amdgcn_mfma_f32_16x16x32_bf16(aa1, cc1, accF1, 0, 0, 0);
    }

    // deg partial: reduce across 16 m-lanes, combine the 4 waves via LDS
    #pragma unroll
    for (int r = 0; r < 4; ++r) {
        float v = dega[r];
        v += __shfl_xor(v, 1);
        v += __shfl_xor(v, 2);
        v += __shfl_xor(v, 4);
        v += __shfl_xor(v, 8);
        if (m == 0) degS[(q * 4 + r) * 4 + w] = v;
    }
    __syncthreads();
    if (t < 16)
        degPart[bj * 2048 + i0 + t] =
            degS[t * 4] + degS[t * 4 + 1] + degS[t * 4 + 2] + degS[t * 4 + 3];

    // partial A@x_last: plain stores (one block per (bj,i,c))
    float* op = outPart + ((size_t)bj * 2048 + i0) * 128;
    #pragma unroll
    for (int r = 0; r < 4; ++r) {
        op[(q * 4 + r) * 128 + w * 32 + m] = accF0[r];
        op[(q * 4 + r) * 128 + w * 32 + 16 + m] = accF1[r];
    }
}

// ---------------- Kernel 3: out = relu(sum_p outPart / sum_p degPart) ----------------
__global__ __launch_bounds__(256) void k3_fin(
    const float* __restrict__ outPart, const float* __restrict__ degPart,
    float* __restrict__ out, int P)
{
    int idx = blockIdx.x * 256 + threadIdx.x;
    int i = idx >> 7, c = idx & 127;
    float s = 0.f, d = 0.f;
    for (int p = 0; p < P; ++p) {
        s += outPart[((size_t)p * 2048 + i) * 128 + c];
        d += degPart[p * 2048 + i];
    }
    out[idx] = fmaxf(s / d, 0.0f);
}

extern "C" void kernel_launch(void* const* d_in, const int* in_sizes, int n_in,
                              void* d_out, int out_size, void* d_ws, size_t ws_size,
                              hipStream_t stream) {
    const float* x     = (const float*)d_in[0];
    const float* W0    = (const float*)d_in[2];
    const float* b0    = (const float*)d_in[3];
    const float* W1    = (const float*)d_in[4];
    const float* b1    = (const float*)d_in[5];
    const float* W2    = (const float*)d_in[6];
    const float* b2    = (const float*)d_in[7];
    const float* temp  = (const float*)d_in[8];
    const float* theta = (const float*)d_in[9];

    // workspace layout
    char* ws = (char*)d_ws;
    unsigned short* emb_bf = (unsigned short*)(ws);            // 262144 B
    unsigned short* xlT_bf = (unsigned short*)(ws + 262144);   // 524288 B
    float* sq      = (float*)(ws + 786432);                    //   8192 B
    float* degPart = (float*)(ws + 794624);                    //  65536 B (8 strips max)
    float* outPart = (float*)(ws + 860160);                    // P*1 MiB

    // pick strip count P (power of 2, <=8) that fits the workspace
    int P = 8;
    while (P > 1 && (size_t)860160 + (size_t)P * 1048576 > ws_size) P >>= 1;
    int iters = 2048 / (P * 64);

    float* out  = (float*)d_out;              // [2048*128]
    float* adjw = (float*)d_out + 262144;     // [2048*2048]

    k1_mlp<<<256, 512, 0, stream>>>(x, W0, b0, W1, b1, W2, b2, emb_bf, xlT_bf, sq);
    k2_adj<<<dim3(128, P), 256, 0, stream>>>(emb_bf, xlT_bf, sq, temp, theta,
                                             outPart, degPart, adjw, iters);
    k3_fin<<<1024, 256, 0, stream>>>(outPart, degPart, out, P);
}